// Round 2
// baseline (49208.084 us; speedup 1.0000x reference)
//
#include <hip/hip_runtime.h>
#include <cmath>

#define N 2048
#define D 512
#define N_ITERS 200
#define BISECT_ITERS 50
#define POWER_ITERS 30

__device__ __forceinline__ float wave_reduce_sum(float x) {
#pragma unroll
  for (int o = 32; o > 0; o >>= 1) x += __shfl_xor(x, o, 64);
  return x;
}

// ---------------- row normalization: Y = fea1/||row||, A = fea2/||row|| ----------------
__global__ __launch_bounds__(256) void rownorm_kernel(const float* __restrict__ fea1,
                                                      const float* __restrict__ fea2,
                                                      float* __restrict__ Y,
                                                      float* __restrict__ A) {
  int b = blockIdx.x;                 // 0..4095
  int row = b & (N - 1);
  const float* src = (b < N) ? fea1 : fea2;
  float* dst = (b < N) ? Y : A;
  const float2* s2 = (const float2*)(src + (size_t)row * D);
  float2* d2 = (float2*)(dst + (size_t)row * D);
  int t = threadIdx.x;                // 256 threads, D/2 = 256 float2
  float2 v = s2[t];
  float ss = v.x * v.x + v.y * v.y;
  ss = wave_reduce_sum(ss);
  __shared__ float sred[4];
  int wid = t >> 6, lane = t & 63;
  if (lane == 0) sred[wid] = ss;
  __syncthreads();
  if (t == 0) sred[0] = sred[0] + sred[1] + sred[2] + sred[3];
  __syncthreads();
  float inv = 1.0f / sqrtf(sred[0]);
  d2[t] = make_float2(v.x * inv, v.y * inv);
}

// ---------------- init X = Z = 1/N, v = 1/N ----------------
__global__ void fill_init(float* __restrict__ X, float* __restrict__ Z, float* __restrict__ v) {
  const float c = 1.0f / (float)N;
  size_t i = (size_t)blockIdx.x * blockDim.x + threadIdx.x;
  size_t total = (size_t)N * N;
  size_t stride = (size_t)gridDim.x * blockDim.x;
  for (size_t idx = i; idx < total; idx += stride) { X[idx] = c; Z[idx] = c; }
  if (i < N) v[i] = c;
}

// ---------------- power iteration pieces (Q v = A (A^T v)) ----------------
__global__ __launch_bounds__(256) void atv_kernel(const float* __restrict__ A,
                                                  const float* __restrict__ v,
                                                  float* __restrict__ u) {
  // u[d] = sum_i A[i][d] * v[i];  grid = 8 blocks of 256 (each block: 64 cols x 4 row-chunks)
  __shared__ float part[4][64];
  int lane = threadIdx.x & 63, wid = threadIdx.x >> 6;
  int d = blockIdx.x * 64 + lane;
  float acc = 0.f;
  int r0 = wid * 512;
  for (int i = 0; i < 512; ++i) {
    int r = r0 + i;
    acc = fmaf(A[(size_t)r * D + d], v[r], acc);
  }
  part[wid][lane] = acc;
  __syncthreads();
  if (wid == 0) u[d] = part[0][lane] + part[1][lane] + part[2][lane] + part[3][lane];
}

__global__ __launch_bounds__(256) void av_kernel(const float* __restrict__ A,
                                                 const float* __restrict__ u,
                                                 float* __restrict__ w) {
  // w[i] = sum_d A[i][d]*u[d]; one wave per row
  int wid = threadIdx.x >> 6, lane = threadIdx.x & 63;
  int row = blockIdx.x * 4 + wid;
  const float* ar = A + (size_t)row * D;
  float acc = 0.f;
#pragma unroll
  for (int e = 0; e < D / 64; ++e) acc = fmaf(ar[e * 64 + lane], u[e * 64 + lane], acc);
  acc = wave_reduce_sum(acc);
  if (lane == 0) w[row] = acc;
}

__global__ __launch_bounds__(1024) void normscale_kernel(const float* __restrict__ w,
                                                         float* __restrict__ v) {
  int t = threadIdx.x;  // 1024 threads, 2 elems each
  float a = w[t], b = w[t + 1024];
  float ss = a * a + b * b;
  ss = wave_reduce_sum(ss);
  __shared__ float sred[16];
  int wid = t >> 6, lane = t & 63;
  if (lane == 0) sred[wid] = ss;
  __syncthreads();
  if (t == 0) {
    float tot = 0.f;
#pragma unroll
    for (int i = 0; i < 16; ++i) tot += sred[i];
    sred[0] = sqrtf(tot) + 1e-12f;
  }
  __syncthreads();
  float nrm = sred[0];
  v[t] = a / nrm;
  v[t + 1024] = b / nrm;
}

__global__ __launch_bounds__(1024) void dotstep_kernel(const float* __restrict__ v,
                                                       const float* __restrict__ w,
                                                       float* __restrict__ step) {
  int t = threadIdx.x;
  float ss = v[t] * w[t] + v[t + 1024] * w[t + 1024];
  ss = wave_reduce_sum(ss);
  __shared__ float sred[16];
  int wid = t >> 6, lane = t & 63;
  if (lane == 0) sred[wid] = ss;
  __syncthreads();
  if (t == 0) {
    float tot = 0.f;
#pragma unroll
    for (int i = 0; i < 16; ++i) tot += sred[i];
    step[0] = 1.0f / (2.0f * tot + 1e-12f);
  }
}

// ---------------- GEMM 1: T = Z @ A - Y   (M=2048, N=512, K=2048, NN) ----------------
__global__ __launch_bounds__(256) void gemm_ta_kernel(const float* __restrict__ Zm,
                                                      const float* __restrict__ A,
                                                      const float* __restrict__ Y,
                                                      float* __restrict__ T) {
  __shared__ float Zs[64][17];
  __shared__ float As[16][64];
  const int tid = threadIdx.x;
  const int row0 = blockIdx.y * 64, col0 = blockIdx.x * 64;
  const int tx = tid & 15, ty = tid >> 4;
  const int lr = tid >> 2;          // 0..63
  const int lk = (tid & 3) * 4;     // 0,4,8,12
  const int ak = tid >> 4;          // 0..15
  const int ac = (tid & 15) * 4;    // 0..60
  float acc[4][4] = {};
  for (int k0 = 0; k0 < N; k0 += 16) {
    float4 z4 = *(const float4*)(Zm + (size_t)(row0 + lr) * N + k0 + lk);
    float4 a4 = *(const float4*)(A + (size_t)(k0 + ak) * D + col0 + ac);
    Zs[lr][lk + 0] = z4.x; Zs[lr][lk + 1] = z4.y; Zs[lr][lk + 2] = z4.z; Zs[lr][lk + 3] = z4.w;
    *(float4*)&As[ak][ac] = a4;
    __syncthreads();
#pragma unroll
    for (int kk = 0; kk < 16; ++kk) {
      float ar[4], br[4];
#pragma unroll
      for (int i = 0; i < 4; ++i) ar[i] = Zs[ty * 4 + i][kk];
#pragma unroll
      for (int j = 0; j < 4; ++j) br[j] = As[kk][tx * 4 + j];
#pragma unroll
      for (int i = 0; i < 4; ++i)
#pragma unroll
        for (int j = 0; j < 4; ++j) acc[i][j] = fmaf(ar[i], br[j], acc[i][j]);
    }
    __syncthreads();
  }
#pragma unroll
  for (int i = 0; i < 4; ++i) {
    int r = row0 + ty * 4 + i;
#pragma unroll
    for (int j = 0; j < 4; ++j) {
      int c = col0 + tx * 4 + j;
      T[(size_t)r * D + c] = acc[i][j] - Y[(size_t)r * D + c];
    }
  }
}

// ---------------- GEMM 2: V = Z - 2*step*(T @ A^T)  (M=2048, N=2048, K=512, NT) ----------------
__global__ __launch_bounds__(256) void gemm_vat_kernel(const float* __restrict__ T,
                                                       const float* __restrict__ A,
                                                       const float* __restrict__ Zm,
                                                       const float* __restrict__ stepp,
                                                       float* __restrict__ V) {
  __shared__ float Ts[64][17];
  __shared__ float As[64][17];
  const int tid = threadIdx.x;
  const int row0 = blockIdx.y * 64, col0 = blockIdx.x * 64;
  const int tx = tid & 15, ty = tid >> 4;
  const int lr = tid >> 2;          // 0..63
  const int lk = (tid & 3) * 4;
  float acc[4][4] = {};
  for (int k0 = 0; k0 < D; k0 += 16) {
    float4 t4 = *(const float4*)(T + (size_t)(row0 + lr) * D + k0 + lk);
    float4 a4 = *(const float4*)(A + (size_t)(col0 + lr) * D + k0 + lk);
    Ts[lr][lk + 0] = t4.x; Ts[lr][lk + 1] = t4.y; Ts[lr][lk + 2] = t4.z; Ts[lr][lk + 3] = t4.w;
    As[lr][lk + 0] = a4.x; As[lr][lk + 1] = a4.y; As[lr][lk + 2] = a4.z; As[lr][lk + 3] = a4.w;
    __syncthreads();
#pragma unroll
    for (int kk = 0; kk < 16; ++kk) {
      float ar[4], br[4];
#pragma unroll
      for (int i = 0; i < 4; ++i) ar[i] = Ts[ty * 4 + i][kk];
#pragma unroll
      for (int j = 0; j < 4; ++j) br[j] = As[tx * 4 + j][kk];
#pragma unroll
      for (int i = 0; i < 4; ++i)
#pragma unroll
        for (int j = 0; j < 4; ++j) acc[i][j] = fmaf(ar[i], br[j], acc[i][j]);
    }
    __syncthreads();
  }
  float s2 = 2.0f * stepp[0];
#pragma unroll
  for (int i = 0; i < 4; ++i) {
    int r = row0 + ty * 4 + i;
#pragma unroll
    for (int j = 0; j < 4; ++j) {
      int c = col0 + tx * 4 + j;
      V[(size_t)r * N + c] = Zm[(size_t)r * N + c] - s2 * acc[i][j];
    }
  }
}

// ---------------- prox: per-row capped-simplex projection + momentum ----------------
__global__ __launch_bounds__(256) void prox_kernel(const float* __restrict__ V,
                                                   float* __restrict__ X,
                                                   float* __restrict__ Z,
                                                   float beta) {
  const int wid = threadIdx.x >> 6, lane = threadIdx.x & 63;
  const int row = blockIdx.x * 4 + wid;
  const float* vrow = V + (size_t)row * N;
  float v[32];
  float mn = 1e30f, mx = -1e30f;
#pragma unroll
  for (int e = 0; e < 32; ++e) {
    v[e] = vrow[e * 64 + lane];
    mn = fminf(mn, v[e]);
    mx = fmaxf(mx, v[e]);
  }
#pragma unroll
  for (int o = 32; o > 0; o >>= 1) {
    mn = fminf(mn, __shfl_xor(mn, o, 64));
    mx = fmaxf(mx, __shfl_xor(mx, o, 64));
  }
  float lo = mn - 1.0f;   // min(v) - upper
  float hi = mx;          // max(v) - lower
#pragma unroll 1
  for (int it = 0; it < BISECT_ITERS; ++it) {
    float mid = 0.5f * (lo + hi);
    float s = 0.f;
#pragma unroll
    for (int e = 0; e < 32; ++e) s += fminf(fmaxf(v[e] - mid, 0.f), 1.f);
    s = wave_reduce_sum(s);
    bool gt = s > 1.0f;
    lo = gt ? mid : lo;
    hi = gt ? hi : mid;
  }
  float tau = 0.5f * (lo + hi);
  float* xrow = X + (size_t)row * N;
  float* zrow = Z + (size_t)row * N;
#pragma unroll
  for (int e = 0; e < 32; ++e) {
    float xn = fminf(fmaxf(v[e] - tau, 0.f), 1.f);
    float xo = xrow[e * 64 + lane];
    xrow[e * 64 + lane] = xn;
    zrow[e * 64 + lane] = xn + beta * (xn - xo);
  }
}

// ---------------- final reduction: out = -mean(T^2) ----------------
__global__ void zero_out_kernel(float* __restrict__ out) {
  if (threadIdx.x == 0 && blockIdx.x == 0) out[0] = 0.f;
}

__global__ __launch_bounds__(256) void mse_reduce_kernel(const float* __restrict__ T,
                                                         float* __restrict__ out) {
  size_t i = (size_t)blockIdx.x * blockDim.x + threadIdx.x;
  size_t total = (size_t)N * D;
  size_t stride = (size_t)gridDim.x * blockDim.x;
  float acc = 0.f;
  for (size_t idx = i; idx < total; idx += stride) {
    float t = T[idx];
    acc = fmaf(t, t, acc);
  }
  acc = wave_reduce_sum(acc);
  __shared__ float sred[4];
  int wid = threadIdx.x >> 6, lane = threadIdx.x & 63;
  if (lane == 0) sred[wid] = acc;
  __syncthreads();
  if (threadIdx.x == 0) {
    float tot = sred[0] + sred[1] + sred[2] + sred[3];
    atomicAdd(out, -tot / (float)((size_t)N * D));
  }
}

extern "C" void kernel_launch(void* const* d_in, const int* in_sizes, int n_in,
                              void* d_out, int out_size, void* d_ws, size_t ws_size,
                              hipStream_t stream) {
  const float* fea1 = (const float*)d_in[0];
  const float* fea2 = (const float*)d_in[1];
  float* out = (float*)d_out;
  float* ws = (float*)d_ws;

  // workspace layout (floats)
  float* A  = ws;                         // nfea2  [N*D]
  float* Y  = A + (size_t)N * D;          // nfea1  [N*D]
  float* Z  = Y + (size_t)N * D;          // [N*N]
  float* X  = Z + (size_t)N * N;          // [N*N]
  float* V  = X + (size_t)N * N;          // [N*N]
  float* T  = V + (size_t)N * N;          // [N*D]
  float* vv = T + (size_t)N * D;          // [N]
  float* uu = vv + N;                     // [D]
  float* wv = uu + D;                     // [N]
  float* sp = wv + N;                     // [1] step

  rownorm_kernel<<<2 * N, 256, 0, stream>>>(fea1, fea2, Y, A);
  fill_init<<<2048, 256, 0, stream>>>(X, Z, vv);

  for (int it = 0; it < POWER_ITERS; ++it) {
    atv_kernel<<<D / 64, 256, 0, stream>>>(A, vv, uu);
    av_kernel<<<N / 4, 256, 0, stream>>>(A, uu, wv);
    normscale_kernel<<<1, 1024, 0, stream>>>(wv, vv);
  }
  atv_kernel<<<D / 64, 256, 0, stream>>>(A, vv, uu);
  av_kernel<<<N / 4, 256, 0, stream>>>(A, uu, wv);
  dotstep_kernel<<<1, 1024, 0, stream>>>(vv, wv, sp);

  float t = 1.0f;
  for (int it = 0; it < N_ITERS; ++it) {
    float tn = 0.5f * (1.0f + sqrtf(1.0f + 4.0f * t * t));
    float beta = (t - 1.0f) / tn;
    t = tn;
    gemm_ta_kernel<<<dim3(D / 64, N / 64), 256, 0, stream>>>(Z, A, Y, T);
    gemm_vat_kernel<<<dim3(N / 64, N / 64), 256, 0, stream>>>(T, A, Z, sp, V);
    prox_kernel<<<N / 4, 256, 0, stream>>>(V, X, Z, beta);
  }

  gemm_ta_kernel<<<dim3(D / 64, N / 64), 256, 0, stream>>>(X, A, Y, T);
  zero_out_kernel<<<1, 64, 0, stream>>>(out);
  mse_reduce_kernel<<<512, 256, 0, stream>>>(T, out);
}

// Round 3
// 14493.983 us; speedup vs baseline: 3.3951x; 3.3951x over previous
//
#include <hip/hip_runtime.h>
#include <cmath>

#define N 2048
#define D 512
#define N_ITERS 200
#define BISECT_ITERS 50
#define POWER_ITERS 30

typedef unsigned short u16;
typedef __bf16 bf16x8 __attribute__((ext_vector_type(8)));
typedef float f32x4 __attribute__((ext_vector_type(4)));

__device__ __forceinline__ float wave_reduce_sum(float x) {
#pragma unroll
  for (int o = 32; o > 0; o >>= 1) x += __shfl_xor(x, o, 64);
  return x;
}

__device__ __forceinline__ u16 f2b(float f) {  // fp32 -> bf16 RNE
  unsigned int u = __float_as_uint(f);
  u = (u + 0x7FFFu + ((u >> 16) & 1u)) >> 16;
  return (u16)u;
}

// ---------------- row normalization: Y = fea1/||row||, A = fea2/||row|| ----------------
__global__ __launch_bounds__(256) void rownorm_kernel(const float* __restrict__ fea1,
                                                      const float* __restrict__ fea2,
                                                      float* __restrict__ Y,
                                                      float* __restrict__ A) {
  int b = blockIdx.x;                 // 0..4095
  int row = b & (N - 1);
  const float* src = (b < N) ? fea1 : fea2;
  float* dst = (b < N) ? Y : A;
  const float2* s2 = (const float2*)(src + (size_t)row * D);
  float2* d2 = (float2*)(dst + (size_t)row * D);
  int t = threadIdx.x;                // 256 threads, D/2 = 256 float2
  float2 v = s2[t];
  float ss = v.x * v.x + v.y * v.y;
  ss = wave_reduce_sum(ss);
  __shared__ float sred[4];
  int wid = t >> 6, lane = t & 63;
  if (lane == 0) sred[wid] = ss;
  __syncthreads();
  if (t == 0) sred[0] = sred[0] + sred[1] + sred[2] + sred[3];
  __syncthreads();
  float inv = 1.0f / sqrtf(sred[0]);
  d2[t] = make_float2(v.x * inv, v.y * inv);
}

// ---------------- prep: Ab = bf16(A), AbT = bf16(A)^T ----------------
__global__ __launch_bounds__(256) void prep_kernel(const float* __restrict__ A,
                                                   u16* __restrict__ Ab,
                                                   u16* __restrict__ AbT) {
  __shared__ float tile[32][33];
  int c0 = blockIdx.x * 32, r0 = blockIdx.y * 32;
  int tid = threadIdx.x;
  int r = tid >> 3, q = tid & 7;      // r 0..31, cols q*4..+3
  float4 v = *(const float4*)&A[(size_t)(r0 + r) * D + c0 + q * 4];
  tile[r][q * 4 + 0] = v.x; tile[r][q * 4 + 1] = v.y;
  tile[r][q * 4 + 2] = v.z; tile[r][q * 4 + 3] = v.w;
  ushort4 b4 = make_ushort4(f2b(v.x), f2b(v.y), f2b(v.z), f2b(v.w));
  *(ushort4*)&Ab[(size_t)(r0 + r) * D + c0 + q * 4] = b4;
  __syncthreads();
  int c = tid >> 3, qq = tid & 7;     // col c, rows qq*4..+3
  ushort4 t4 = make_ushort4(f2b(tile[qq * 4 + 0][c]), f2b(tile[qq * 4 + 1][c]),
                            f2b(tile[qq * 4 + 2][c]), f2b(tile[qq * 4 + 3][c]));
  *(ushort4*)&AbT[(size_t)(c0 + c) * N + r0 + qq * 4] = t4;
}

// ---------------- init X = ZV = 1/N (fp32), Zb = bf16(1/N), v = 1/N ----------------
__global__ void fill_init(float* __restrict__ X, float* __restrict__ ZV,
                          u16* __restrict__ Zb, float* __restrict__ v) {
  const float c = 1.0f / (float)N;
  const u16 cb = f2b(c);
  size_t i = (size_t)blockIdx.x * blockDim.x + threadIdx.x;
  size_t total = (size_t)N * N;
  size_t stride = (size_t)gridDim.x * blockDim.x;
  for (size_t idx = i; idx < total; idx += stride) { X[idx] = c; ZV[idx] = c; Zb[idx] = cb; }
  if (i < N) v[i] = c;
}

// ---------------- power iteration pieces (Q v = A (A^T v)), fp32 ----------------
__global__ __launch_bounds__(256) void atv_kernel(const float* __restrict__ A,
                                                  const float* __restrict__ v,
                                                  float* __restrict__ u) {
  __shared__ float part[4][64];
  int lane = threadIdx.x & 63, wid = threadIdx.x >> 6;
  int d = blockIdx.x * 64 + lane;
  float acc = 0.f;
  int r0 = wid * 512;
  for (int i = 0; i < 512; ++i) {
    int r = r0 + i;
    acc = fmaf(A[(size_t)r * D + d], v[r], acc);
  }
  part[wid][lane] = acc;
  __syncthreads();
  if (wid == 0) u[d] = part[0][lane] + part[1][lane] + part[2][lane] + part[3][lane];
}

__global__ __launch_bounds__(256) void av_kernel(const float* __restrict__ A,
                                                 const float* __restrict__ u,
                                                 float* __restrict__ w) {
  int wid = threadIdx.x >> 6, lane = threadIdx.x & 63;
  int row = blockIdx.x * 4 + wid;
  const float* ar = A + (size_t)row * D;
  float acc = 0.f;
#pragma unroll
  for (int e = 0; e < D / 64; ++e) acc = fmaf(ar[e * 64 + lane], u[e * 64 + lane], acc);
  acc = wave_reduce_sum(acc);
  if (lane == 0) w[row] = acc;
}

__global__ __launch_bounds__(1024) void normscale_kernel(const float* __restrict__ w,
                                                         float* __restrict__ v) {
  int t = threadIdx.x;
  float a = w[t], b = w[t + 1024];
  float ss = a * a + b * b;
  ss = wave_reduce_sum(ss);
  __shared__ float sred[16];
  int wid = t >> 6, lane = t & 63;
  if (lane == 0) sred[wid] = ss;
  __syncthreads();
  if (t == 0) {
    float tot = 0.f;
#pragma unroll
    for (int i = 0; i < 16; ++i) tot += sred[i];
    sred[0] = sqrtf(tot) + 1e-12f;
  }
  __syncthreads();
  float nrm = sred[0];
  v[t] = a / nrm;
  v[t + 1024] = b / nrm;
}

__global__ __launch_bounds__(1024) void dotstep_kernel(const float* __restrict__ v,
                                                       const float* __restrict__ w,
                                                       float* __restrict__ step) {
  int t = threadIdx.x;
  float ss = v[t] * w[t] + v[t + 1024] * w[t + 1024];
  ss = wave_reduce_sum(ss);
  __shared__ float sred[16];
  int wid = t >> 6, lane = t & 63;
  if (lane == 0) sred[wid] = ss;
  __syncthreads();
  if (t == 0) {
    float tot = 0.f;
#pragma unroll
    for (int i = 0; i < 16; ++i) tot += sred[i];
    step[0] = 1.0f / (2.0f * tot + 1e-12f);
  }
}

// ================= bf16 MFMA GEMMs =================
// 64x64 tile, 256 threads = 4 waves (2x2), each wave 32x32 = 2x2 frags of 16x16,
// BK=32 (one mfma_16x16x32 per frag per K-step). LDS padded to 40 ushorts/row
// (80 B stride -> 2-way bank aliasing = free). Bs stored [col][k] so the B-frag
// (lane holds B[k][col], 8 consecutive k) is a ds_read_b128, fed from pre-
// transposed AbT (GEMM1) / row-major Ab (GEMM2: B[k][n] = A[n][k]).
#define LDK 40

// GEMM1: Tb = bf16( Zb @ A  - Y ),  M=2048, Ncols=512, K=2048
__global__ __launch_bounds__(256) void gemm1_mfma(const u16* __restrict__ Zb,
                                                  const u16* __restrict__ AbT,
                                                  const float* __restrict__ Y,
                                                  u16* __restrict__ Tb) {
  __shared__ u16 As[64 * LDK];
  __shared__ u16 Bs[64 * LDK];
  const int tid = threadIdx.x;
  const int row0 = blockIdx.y * 64, col0 = blockIdx.x * 64;
  const int lane = tid & 63, wid = tid >> 6;
  const int wr = (wid >> 1) * 32, wc = (wid & 1) * 32;
  const int srow = tid >> 2, skoff = (tid & 3) * 8;
  const int fr = lane & 15, fk = (lane >> 4) * 8;
  const size_t abase = (size_t)(row0 + srow) * N + skoff;
  const size_t bbase = (size_t)(col0 + srow) * N + skoff;
  const int swr = srow * LDK + skoff;
  f32x4 acc[2][2] = {};
  for (int k0 = 0; k0 < N; k0 += 32) {
    *(ulonglong2*)&As[swr] = *(const ulonglong2*)&Zb[abase + k0];
    *(ulonglong2*)&Bs[swr] = *(const ulonglong2*)&AbT[bbase + k0];
    __syncthreads();
    bf16x8 af[2], bg[2];
#pragma unroll
    for (int i = 0; i < 2; ++i) af[i] = *(const bf16x8*)&As[(wr + i * 16 + fr) * LDK + fk];
#pragma unroll
    for (int j = 0; j < 2; ++j) bg[j] = *(const bf16x8*)&Bs[(wc + j * 16 + fr) * LDK + fk];
#pragma unroll
    for (int i = 0; i < 2; ++i)
#pragma unroll
      for (int j = 0; j < 2; ++j)
        acc[i][j] = __builtin_amdgcn_mfma_f32_16x16x32_bf16(af[i], bg[j], acc[i][j], 0, 0, 0);
    __syncthreads();
  }
  const int drb = (lane >> 4) * 4, dc = lane & 15;
#pragma unroll
  for (int i = 0; i < 2; ++i)
#pragma unroll
    for (int j = 0; j < 2; ++j)
#pragma unroll
      for (int g = 0; g < 4; ++g) {
        int r = row0 + wr + i * 16 + drb + g;
        int c = col0 + wc + j * 16 + dc;
        float t = acc[i][j][g] - Y[(size_t)r * D + c];
        Tb[(size_t)r * D + c] = f2b(t);
      }
}

// GEMM2 (in-place): ZV = ZV - 2*step*(Tb @ Ab^T),  M=N=2048, K=512
__global__ __launch_bounds__(256) void gemm2_mfma(const u16* __restrict__ Tb,
                                                  const u16* __restrict__ Ab,
                                                  const float* __restrict__ stepp,
                                                  float* __restrict__ ZV) {
  __shared__ u16 As[64 * LDK];
  __shared__ u16 Bs[64 * LDK];
  const int tid = threadIdx.x;
  const int row0 = blockIdx.y * 64, col0 = blockIdx.x * 64;
  const int lane = tid & 63, wid = tid >> 6;
  const int wr = (wid >> 1) * 32, wc = (wid & 1) * 32;
  const int srow = tid >> 2, skoff = (tid & 3) * 8;
  const int fr = lane & 15, fk = (lane >> 4) * 8;
  const size_t abase = (size_t)(row0 + srow) * D + skoff;
  const size_t bbase = (size_t)(col0 + srow) * D + skoff;
  const int swr = srow * LDK + skoff;
  f32x4 acc[2][2] = {};
  for (int k0 = 0; k0 < D; k0 += 32) {
    *(ulonglong2*)&As[swr] = *(const ulonglong2*)&Tb[abase + k0];
    *(ulonglong2*)&Bs[swr] = *(const ulonglong2*)&Ab[bbase + k0];
    __syncthreads();
    bf16x8 af[2], bg[2];
#pragma unroll
    for (int i = 0; i < 2; ++i) af[i] = *(const bf16x8*)&As[(wr + i * 16 + fr) * LDK + fk];
#pragma unroll
    for (int j = 0; j < 2; ++j) bg[j] = *(const bf16x8*)&Bs[(wc + j * 16 + fr) * LDK + fk];
#pragma unroll
    for (int i = 0; i < 2; ++i)
#pragma unroll
      for (int j = 0; j < 2; ++j)
        acc[i][j] = __builtin_amdgcn_mfma_f32_16x16x32_bf16(af[i], bg[j], acc[i][j], 0, 0, 0);
    __syncthreads();
  }
  float s2 = 2.0f * stepp[0];
  const int drb = (lane >> 4) * 4, dc = lane & 15;
#pragma unroll
  for (int i = 0; i < 2; ++i)
#pragma unroll
    for (int j = 0; j < 2; ++j)
#pragma unroll
      for (int g = 0; g < 4; ++g) {
        int r = row0 + wr + i * 16 + drb + g;
        int c = col0 + wc + j * 16 + dc;
        size_t idx = (size_t)r * N + c;
        ZV[idx] = ZV[idx] - s2 * acc[i][j][g];   // elementwise same-index: in-place safe
      }
}

// ---------------- prox: per-row capped-simplex projection + momentum ----------------
__global__ __launch_bounds__(256) void prox_kernel(float* __restrict__ ZV,
                                                   float* __restrict__ X,
                                                   u16* __restrict__ Zb,
                                                   float beta) {
  const int wid = threadIdx.x >> 6, lane = threadIdx.x & 63;
  const int row = blockIdx.x * 4 + wid;
  float* vrow = ZV + (size_t)row * N;
  float v[32];
  float mn = 1e30f, mx = -1e30f;
#pragma unroll
  for (int e = 0; e < 32; ++e) {
    v[e] = vrow[e * 64 + lane];
    mn = fminf(mn, v[e]);
    mx = fmaxf(mx, v[e]);
  }
#pragma unroll
  for (int o = 32; o > 0; o >>= 1) {
    mn = fminf(mn, __shfl_xor(mn, o, 64));
    mx = fmaxf(mx, __shfl_xor(mx, o, 64));
  }
  float lo = mn - 1.0f;
  float hi = mx;
#pragma unroll 1
  for (int it = 0; it < BISECT_ITERS; ++it) {
    float mid = 0.5f * (lo + hi);
    float s = 0.f;
#pragma unroll
    for (int e = 0; e < 32; ++e) s += fminf(fmaxf(v[e] - mid, 0.f), 1.f);
    s = wave_reduce_sum(s);
    bool gt = s > 1.0f;
    lo = gt ? mid : lo;
    hi = gt ? hi : mid;
  }
  float tau = 0.5f * (lo + hi);
  float* xrow = X + (size_t)row * N;
  u16* zbrow = Zb + (size_t)row * N;
#pragma unroll
  for (int e = 0; e < 32; ++e) {
    int idx = e * 64 + lane;
    float xn = fminf(fmaxf(v[e] - tau, 0.f), 1.f);
    float xo = xrow[idx];
    float zn = xn + beta * (xn - xo);
    xrow[idx] = xn;
    vrow[idx] = zn;          // ZV now holds Z for next iteration
    zbrow[idx] = f2b(zn);
  }
}

// ---------------- final fp32 GEMM (exact objective): T = X @ A - Y ----------------
__global__ __launch_bounds__(256) void gemm_ta_kernel(const float* __restrict__ Zm,
                                                      const float* __restrict__ A,
                                                      const float* __restrict__ Y,
                                                      float* __restrict__ T) {
  __shared__ float Zs[64][17];
  __shared__ float As[16][64];
  const int tid = threadIdx.x;
  const int row0 = blockIdx.y * 64, col0 = blockIdx.x * 64;
  const int tx = tid & 15, ty = tid >> 4;
  const int lr = tid >> 2;
  const int lk = (tid & 3) * 4;
  const int ak = tid >> 4;
  const int ac = (tid & 15) * 4;
  float acc[4][4] = {};
  for (int k0 = 0; k0 < N; k0 += 16) {
    float4 z4 = *(const float4*)(Zm + (size_t)(row0 + lr) * N + k0 + lk);
    float4 a4 = *(const float4*)(A + (size_t)(k0 + ak) * D + col0 + ac);
    Zs[lr][lk + 0] = z4.x; Zs[lr][lk + 1] = z4.y; Zs[lr][lk + 2] = z4.z; Zs[lr][lk + 3] = z4.w;
    *(float4*)&As[ak][ac] = a4;
    __syncthreads();
#pragma unroll
    for (int kk = 0; kk < 16; ++kk) {
      float ar[4], br[4];
#pragma unroll
      for (int i = 0; i < 4; ++i) ar[i] = Zs[ty * 4 + i][kk];
#pragma unroll
      for (int j = 0; j < 4; ++j) br[j] = As[kk][tx * 4 + j];
#pragma unroll
      for (int i = 0; i < 4; ++i)
#pragma unroll
        for (int j = 0; j < 4; ++j) acc[i][j] = fmaf(ar[i], br[j], acc[i][j]);
    }
    __syncthreads();
  }
#pragma unroll
  for (int i = 0; i < 4; ++i) {
    int r = row0 + ty * 4 + i;
#pragma unroll
    for (int j = 0; j < 4; ++j) {
      int c = col0 + tx * 4 + j;
      T[(size_t)r * D + c] = acc[i][j] - Y[(size_t)r * D + c];
    }
  }
}

// ---------------- final reduction: out = -mean(T^2) ----------------
__global__ void zero_out_kernel(float* __restrict__ out) {
  if (threadIdx.x == 0 && blockIdx.x == 0) out[0] = 0.f;
}

__global__ __launch_bounds__(256) void mse_reduce_kernel(const float* __restrict__ T,
                                                         float* __restrict__ out) {
  size_t i = (size_t)blockIdx.x * blockDim.x + threadIdx.x;
  size_t total = (size_t)N * D;
  size_t stride = (size_t)gridDim.x * blockDim.x;
  float acc = 0.f;
  for (size_t idx = i; idx < total; idx += stride) {
    float t = T[idx];
    acc = fmaf(t, t, acc);
  }
  acc = wave_reduce_sum(acc);
  __shared__ float sred[4];
  int wid = threadIdx.x >> 6, lane = threadIdx.x & 63;
  if (lane == 0) sred[wid] = acc;
  __syncthreads();
  if (threadIdx.x == 0) {
    float tot = sred[0] + sred[1] + sred[2] + sred[3];
    atomicAdd(out, -tot / (float)((size_t)N * D));
  }
}

extern "C" void kernel_launch(void* const* d_in, const int* in_sizes, int n_in,
                              void* d_out, int out_size, void* d_ws, size_t ws_size,
                              hipStream_t stream) {
  const float* fea1 = (const float*)d_in[0];
  const float* fea2 = (const float*)d_in[1];
  float* out = (float*)d_out;
  float* ws = (float*)d_ws;

  // workspace layout (all offsets 16B-aligned)
  float* A   = ws;                        // [N*D] fp32 nfea2
  float* Y   = A + (size_t)N * D;         // [N*D] fp32 nfea1
  float* ZV  = Y + (size_t)N * D;         // [N*N] fp32: Z and V share (elementwise)
  float* X   = ZV + (size_t)N * N;        // [N*N] fp32
  float* T   = X + (size_t)N * N;         // [N*D] fp32 (final objective)
  float* vv  = T + (size_t)N * D;         // [N]
  float* uu  = vv + N;                    // [D]
  float* wv  = uu + D;                    // [N]
  float* sp  = wv + N;                    // [16] step (padded)
  u16* Zb    = (u16*)(sp + 16);           // [N*N] bf16 Z
  u16* Tb    = Zb + (size_t)N * N;        // [N*D] bf16 T
  u16* Ab    = Tb + (size_t)N * D;        // [N*D] bf16 A
  u16* AbT   = Ab + (size_t)N * D;        // [D*N] bf16 A^T
  // total ~58.3 MB

  rownorm_kernel<<<2 * N, 256, 0, stream>>>(fea1, fea2, Y, A);
  prep_kernel<<<dim3(D / 32, N / 32), 256, 0, stream>>>(A, Ab, AbT);
  fill_init<<<2048, 256, 0, stream>>>(X, ZV, Zb, vv);

  for (int it = 0; it < POWER_ITERS; ++it) {
    atv_kernel<<<D / 64, 256, 0, stream>>>(A, vv, uu);
    av_kernel<<<N / 4, 256, 0, stream>>>(A, uu, wv);
    normscale_kernel<<<1, 1024, 0, stream>>>(wv, vv);
  }
  atv_kernel<<<D / 64, 256, 0, stream>>>(A, vv, uu);
  av_kernel<<<N / 4, 256, 0, stream>>>(A, uu, wv);
  dotstep_kernel<<<1, 1024, 0, stream>>>(vv, wv, sp);

  float t = 1.0f;
  for (int it = 0; it < N_ITERS; ++it) {
    float tn = 0.5f * (1.0f + sqrtf(1.0f + 4.0f * t * t));
    float beta = (t - 1.0f) / tn;
    t = tn;
    gemm1_mfma<<<dim3(D / 64, N / 64), 256, 0, stream>>>(Zb, AbT, Y, Tb);
    gemm2_mfma<<<dim3(N / 64, N / 64), 256, 0, stream>>>(Tb, Ab, sp, ZV);
    prox_kernel<<<N / 4, 256, 0, stream>>>(ZV, X, Zb, beta);
  }

  // exact fp32 objective on the final X
  gemm_ta_kernel<<<dim3(D / 64, N / 64), 256, 0, stream>>>(X, A, Y, T);
  zero_out_kernel<<<1, 64, 0, stream>>>(out);
  mse_reduce_kernel<<<512, 256, 0, stream>>>(T, out);
}

// Round 4
// 11932.954 us; speedup vs baseline: 4.1237x; 1.2146x over previous
//
#include <hip/hip_runtime.h>
#include <cmath>

#define N 2048
#define D 512
#define N_ITERS 200
#define BISECT_ITERS 50
#define POWER_ITERS 30

typedef unsigned short u16;
typedef __bf16 bf16x8 __attribute__((ext_vector_type(8)));
typedef float f32x4 __attribute__((ext_vector_type(4)));

__device__ __forceinline__ float wave_reduce_sum(float x) {
#pragma unroll
  for (int o = 32; o > 0; o >>= 1) x += __shfl_xor(x, o, 64);
  return x;
}

__device__ __forceinline__ u16 f2b(float f) {  // fp32 -> bf16 RNE
  unsigned int u = __float_as_uint(f);
  u = (u + 0x7FFFu + ((u >> 16) & 1u)) >> 16;
  return (u16)u;
}

__device__ __forceinline__ float b2f(unsigned int lo16) {
  return __uint_as_float(lo16 << 16);
}

// async 16B global->LDS (wave-uniform LDS base + lane*16)
__device__ __forceinline__ void gload16(const u16* g, u16* l) {
  __builtin_amdgcn_global_load_lds(
      (const __attribute__((address_space(1))) unsigned int*)g,
      (__attribute__((address_space(3))) unsigned int*)l, 16, 0, 0);
}

// ---------------- row normalization: Y = fea1/||row||, A = fea2/||row|| ----------------
__global__ __launch_bounds__(256) void rownorm_kernel(const float* __restrict__ fea1,
                                                      const float* __restrict__ fea2,
                                                      float* __restrict__ Y,
                                                      float* __restrict__ A) {
  int b = blockIdx.x;
  int row = b & (N - 1);
  const float* src = (b < N) ? fea1 : fea2;
  float* dst = (b < N) ? Y : A;
  const float2* s2 = (const float2*)(src + (size_t)row * D);
  float2* d2 = (float2*)(dst + (size_t)row * D);
  int t = threadIdx.x;
  float2 v = s2[t];
  float ss = v.x * v.x + v.y * v.y;
  ss = wave_reduce_sum(ss);
  __shared__ float sred[4];
  int wid = t >> 6, lane = t & 63;
  if (lane == 0) sred[wid] = ss;
  __syncthreads();
  if (t == 0) sred[0] = sred[0] + sred[1] + sred[2] + sred[3];
  __syncthreads();
  float inv = 1.0f / sqrtf(sred[0]);
  d2[t] = make_float2(v.x * inv, v.y * inv);
}

// ---------------- prep: Ab = bf16(A), AbT = bf16(A)^T ----------------
__global__ __launch_bounds__(256) void prep_kernel(const float* __restrict__ A,
                                                   u16* __restrict__ Ab,
                                                   u16* __restrict__ AbT) {
  __shared__ float tile[32][33];
  int c0 = blockIdx.x * 32, r0 = blockIdx.y * 32;
  int tid = threadIdx.x;
  int r = tid >> 3, q = tid & 7;
  float4 v = *(const float4*)&A[(size_t)(r0 + r) * D + c0 + q * 4];
  tile[r][q * 4 + 0] = v.x; tile[r][q * 4 + 1] = v.y;
  tile[r][q * 4 + 2] = v.z; tile[r][q * 4 + 3] = v.w;
  ushort4 b4 = make_ushort4(f2b(v.x), f2b(v.y), f2b(v.z), f2b(v.w));
  *(ushort4*)&Ab[(size_t)(r0 + r) * D + c0 + q * 4] = b4;
  __syncthreads();
  int c = tid >> 3, qq = tid & 7;
  ushort4 t4 = make_ushort4(f2b(tile[qq * 4 + 0][c]), f2b(tile[qq * 4 + 1][c]),
                            f2b(tile[qq * 4 + 2][c]), f2b(tile[qq * 4 + 3][c]));
  *(ushort4*)&AbT[(size_t)(c0 + c) * N + r0 + qq * 4] = t4;
}

// ---------------- init X = 1/N (fp32), Zb = bf16(1/N), v = 1/N ----------------
__global__ void fill_init(float* __restrict__ X, u16* __restrict__ Zb, float* __restrict__ v) {
  const float c = 1.0f / (float)N;
  const u16 cb = f2b(c);
  size_t i = (size_t)blockIdx.x * blockDim.x + threadIdx.x;
  size_t total = (size_t)N * N;
  size_t stride = (size_t)gridDim.x * blockDim.x;
  for (size_t idx = i; idx < total; idx += stride) { X[idx] = c; Zb[idx] = cb; }
  if (i < N) v[i] = c;
}

// ---------------- power iteration pieces (Q v = A (A^T v)), fp32 ----------------
__global__ __launch_bounds__(256) void atv_kernel(const float* __restrict__ A,
                                                  const float* __restrict__ v,
                                                  float* __restrict__ u) {
  __shared__ float part[4][64];
  int lane = threadIdx.x & 63, wid = threadIdx.x >> 6;
  int d = blockIdx.x * 64 + lane;
  float acc = 0.f;
  int r0 = wid * 512;
  for (int i = 0; i < 512; ++i) {
    int r = r0 + i;
    acc = fmaf(A[(size_t)r * D + d], v[r], acc);
  }
  part[wid][lane] = acc;
  __syncthreads();
  if (wid == 0) u[d] = part[0][lane] + part[1][lane] + part[2][lane] + part[3][lane];
}

__global__ __launch_bounds__(256) void av_kernel(const float* __restrict__ A,
                                                 const float* __restrict__ u,
                                                 float* __restrict__ w) {
  int wid = threadIdx.x >> 6, lane = threadIdx.x & 63;
  int row = blockIdx.x * 4 + wid;
  const float* ar = A + (size_t)row * D;
  float acc = 0.f;
#pragma unroll
  for (int e = 0; e < D / 64; ++e) acc = fmaf(ar[e * 64 + lane], u[e * 64 + lane], acc);
  acc = wave_reduce_sum(acc);
  if (lane == 0) w[row] = acc;
}

__global__ __launch_bounds__(1024) void normscale_kernel(const float* __restrict__ w,
                                                         float* __restrict__ v) {
  int t = threadIdx.x;
  float a = w[t], b = w[t + 1024];
  float ss = a * a + b * b;
  ss = wave_reduce_sum(ss);
  __shared__ float sred[16];
  int wid = t >> 6, lane = t & 63;
  if (lane == 0) sred[wid] = ss;
  __syncthreads();
  if (t == 0) {
    float tot = 0.f;
#pragma unroll
    for (int i = 0; i < 16; ++i) tot += sred[i];
    sred[0] = sqrtf(tot) + 1e-12f;
  }
  __syncthreads();
  float nrm = sred[0];
  v[t] = a / nrm;
  v[t + 1024] = b / nrm;
}

__global__ __launch_bounds__(1024) void dotstep_kernel(const float* __restrict__ v,
                                                       const float* __restrict__ w,
                                                       float* __restrict__ step) {
  int t = threadIdx.x;
  float ss = v[t] * w[t] + v[t + 1024] * w[t + 1024];
  ss = wave_reduce_sum(ss);
  __shared__ float sred[16];
  int wid = t >> 6, lane = t & 63;
  if (lane == 0) sred[wid] = ss;
  __syncthreads();
  if (t == 0) {
    float tot = 0.f;
#pragma unroll
    for (int i = 0; i < 16; ++i) tot += sred[i];
    step[0] = 1.0f / (2.0f * tot + 1e-12f);
  }
}

// ================= MFMA GEMMs: gload_lds + XOR-swizzle + 2-phase dbuf =================
// LDS tile rows of 64 u16 (128B = 8 slots of 16B). Logical k-slot s of row r is stored
// at physical slot s^(r&7) (both on the staged global source address and the ds_read
// address -> involution cancels; banks spread 32-wide, 2-way max = free).

// GEMM1: Tb = bf16( Zb @ A - Y ), M=2048, cols=512, K=2048. 64x64 tile, BK=64, 32 steps.
__global__ __launch_bounds__(256) void gemm1_mfma(const u16* __restrict__ Zb,
                                                  const u16* __restrict__ AbT,
                                                  const float* __restrict__ Y,
                                                  u16* __restrict__ Tb) {
  __shared__ u16 lds[2 * 8192];  // [buf][A 4096 | B 4096]
  const int tid = threadIdx.x, lane = tid & 63, wid = tid >> 6;
  const int row0 = blockIdx.y * 64, col0 = blockIdx.x * 64;
  const int wr = (wid >> 1) * 32, wc = (wid & 1) * 32;
  const int fr = lane & 15, h = lane >> 4;
  const int sr = lane >> 3, ss = lane & 7;
  const int sk = (ss ^ sr) << 3;  // swizzled k-elem offset for staging
  f32x4 acc[2][2] = {};

#define G1_STAGE(BUF, T)                                                        \
  {                                                                             \
    int k0 = (T) * 64;                                                          \
    _Pragma("unroll") for (int q = 0; q < 2; ++q) {                             \
      int m = wid * 2 + q;                                                      \
      gload16(&Zb[(size_t)(row0 + m * 8 + sr) * 2048 + k0 + sk],                \
              &lds[(BUF) * 8192 + m * 512]);                                    \
      gload16(&AbT[(size_t)(col0 + m * 8 + sr) * 2048 + k0 + sk],               \
              &lds[(BUF) * 8192 + 4096 + m * 512]);                             \
    }                                                                           \
  }

  G1_STAGE(0, 0);
  __syncthreads();
#pragma unroll 2
  for (int t = 0; t < 32; ++t) {
    const int buf = (t & 1) * 8192;
    if (t < 31) G1_STAGE((t & 1) ^ 1, t + 1);
    bf16x8 af[2][2], bg[2][2];
#pragma unroll
    for (int i = 0; i < 2; ++i) {
      int r = wr + i * 16 + fr;
#pragma unroll
      for (int ks = 0; ks < 2; ++ks)
        af[i][ks] = *(const bf16x8*)&lds[buf + r * 64 + ((((ks << 2) + h) ^ (fr & 7)) << 3)];
    }
#pragma unroll
    for (int j = 0; j < 2; ++j) {
      int c = wc + j * 16 + fr;
#pragma unroll
      for (int ks = 0; ks < 2; ++ks)
        bg[j][ks] = *(const bf16x8*)&lds[buf + 4096 + c * 64 + ((((ks << 2) + h) ^ (fr & 7)) << 3)];
    }
#pragma unroll
    for (int ks = 0; ks < 2; ++ks)
#pragma unroll
      for (int i = 0; i < 2; ++i)
#pragma unroll
        for (int j = 0; j < 2; ++j)
          acc[i][j] = __builtin_amdgcn_mfma_f32_16x16x32_bf16(af[i][ks], bg[j][ks], acc[i][j], 0, 0, 0);
    __syncthreads();
  }
#pragma unroll
  for (int i = 0; i < 2; ++i)
#pragma unroll
    for (int j = 0; j < 2; ++j)
#pragma unroll
      for (int g = 0; g < 4; ++g) {
        int r = row0 + wr + i * 16 + h * 4 + g;
        int c = col0 + wc + j * 16 + fr;
        Tb[(size_t)r * D + c] = f2b(acc[i][j][g] - Y[(size_t)r * D + c]);
      }
#undef G1_STAGE
}

// GEMM2: Gb = bf16( Tb @ Ab^T ), M=N=2048, K=512. 128x128 tile, BK=64, 8 steps.
__global__ __launch_bounds__(256) void gemm2_mfma(const u16* __restrict__ Tb,
                                                  const u16* __restrict__ Ab,
                                                  u16* __restrict__ Gb) {
  __shared__ u16 lds[2 * 16384];  // [buf][A 8192 | B 8192]
  const int tid = threadIdx.x, lane = tid & 63, wid = tid >> 6;
  const int row0 = blockIdx.y * 128, col0 = blockIdx.x * 128;
  const int wr = (wid >> 1) * 64, wc = (wid & 1) * 64;
  const int fr = lane & 15, h = lane >> 4;
  const int sr = lane >> 3, ss = lane & 7;
  const int sk = (ss ^ sr) << 3;
  f32x4 acc[4][4] = {};

#define G2_STAGE(BUF, T)                                                        \
  {                                                                             \
    int k0 = (T) * 64;                                                          \
    _Pragma("unroll") for (int q = 0; q < 4; ++q) {                             \
      int m = wid * 4 + q;                                                      \
      gload16(&Tb[(size_t)(row0 + m * 8 + sr) * 512 + k0 + sk],                 \
              &lds[(BUF) * 16384 + m * 512]);                                   \
      gload16(&Ab[(size_t)(col0 + m * 8 + sr) * 512 + k0 + sk],                 \
              &lds[(BUF) * 16384 + 8192 + m * 512]);                            \
    }                                                                           \
  }

  G2_STAGE(0, 0);
  __syncthreads();
#pragma unroll 2
  for (int t = 0; t < 8; ++t) {
    const int buf = (t & 1) * 16384;
    if (t < 7) G2_STAGE((t & 1) ^ 1, t + 1);
    bf16x8 af[4][2], bg[4][2];
#pragma unroll
    for (int i = 0; i < 4; ++i) {
      int r = wr + i * 16 + fr;
#pragma unroll
      for (int ks = 0; ks < 2; ++ks)
        af[i][ks] = *(const bf16x8*)&lds[buf + r * 64 + ((((ks << 2) + h) ^ (fr & 7)) << 3)];
    }
#pragma unroll
    for (int j = 0; j < 4; ++j) {
      int c = wc + j * 16 + fr;
#pragma unroll
      for (int ks = 0; ks < 2; ++ks)
        bg[j][ks] = *(const bf16x8*)&lds[buf + 8192 + c * 64 + ((((ks << 2) + h) ^ (fr & 7)) << 3)];
    }
#pragma unroll
    for (int ks = 0; ks < 2; ++ks)
#pragma unroll
      for (int i = 0; i < 4; ++i)
#pragma unroll
        for (int j = 0; j < 4; ++j)
          acc[i][j] = __builtin_amdgcn_mfma_f32_16x16x32_bf16(af[i][ks], bg[j][ks], acc[i][j], 0, 0, 0);
    __syncthreads();
  }
#pragma unroll
  for (int i = 0; i < 4; ++i)
#pragma unroll
    for (int j = 0; j < 4; ++j)
#pragma unroll
      for (int g = 0; g < 4; ++g) {
        int r = row0 + wr + i * 16 + h * 4 + g;
        int c = col0 + wc + j * 16 + fr;
        Gb[(size_t)r * N + c] = f2b(acc[i][j][g]);
      }
#undef G2_STAGE
}

// ---------------- prox: v = z - 2s*g; capped-simplex projection; momentum ----------------
__global__ __launch_bounds__(256) void prox_kernel(const u16* __restrict__ Gb,
                                                   u16* __restrict__ Zb,
                                                   float* __restrict__ X,
                                                   const float* __restrict__ stepp,
                                                   float beta) {
  const int wid = threadIdx.x >> 6, lane = threadIdx.x & 63;
  const int row = blockIdx.x * 4 + wid;
  const size_t rb = (size_t)row * N;
  const float s2 = 2.0f * stepp[0];
  float v[32], xo[32];
  float mn = 1e30f, mx = -1e30f;
#pragma unroll
  for (int c = 0; c < 4; ++c) {
    const int base = c * 512 + lane * 8;
    uint4 zu = *(const uint4*)&Zb[rb + base];
    uint4 gu = *(const uint4*)&Gb[rb + base];
    float4 x0 = *(const float4*)&X[rb + base];
    float4 x1 = *(const float4*)&X[rb + base + 4];
    const unsigned int zw[4] = {zu.x, zu.y, zu.z, zu.w};
    const unsigned int gw[4] = {gu.x, gu.y, gu.z, gu.w};
    const float xs[8] = {x0.x, x0.y, x0.z, x0.w, x1.x, x1.y, x1.z, x1.w};
#pragma unroll
    for (int w = 0; w < 4; ++w) {
      int e = c * 8 + w * 2;
      float v0 = b2f(zw[w] & 0xffffu) - s2 * b2f(gw[w] & 0xffffu);
      float v1 = __uint_as_float(zw[w] & 0xffff0000u) - s2 * __uint_as_float(gw[w] & 0xffff0000u);
      v[e] = v0; v[e + 1] = v1;
      xo[e] = xs[w * 2]; xo[e + 1] = xs[w * 2 + 1];
      mn = fminf(mn, fminf(v0, v1));
      mx = fmaxf(mx, fmaxf(v0, v1));
    }
  }
#pragma unroll
  for (int o = 32; o > 0; o >>= 1) {
    mn = fminf(mn, __shfl_xor(mn, o, 64));
    mx = fmaxf(mx, __shfl_xor(mx, o, 64));
  }
  float lo = mn - 1.0f;   // min(v) - upper
  float hi = mx;          // max(v) - lower
#pragma unroll 1
  for (int it = 0; it < BISECT_ITERS; ++it) {
    float mid = 0.5f * (lo + hi);
    float s = 0.f;
#pragma unroll
    for (int e = 0; e < 32; ++e) s += fminf(fmaxf(v[e] - mid, 0.f), 1.f);
    s = wave_reduce_sum(s);
    bool gt = s > 1.0f;
    lo = gt ? mid : lo;
    hi = gt ? hi : mid;
  }
  float tau = 0.5f * (lo + hi);
#pragma unroll
  for (int c = 0; c < 4; ++c) {
    const int base = c * 512 + lane * 8;
    float xn[8];
    unsigned int zp[4];
#pragma unroll
    for (int q = 0; q < 8; ++q) {
      int e = c * 8 + q;
      float x = fminf(fmaxf(v[e] - tau, 0.f), 1.f);
      float zn = x + beta * (x - xo[e]);
      xn[q] = x;
      if (q & 1) zp[q >> 1] |= (unsigned int)f2b(zn) << 16;
      else       zp[q >> 1] = f2b(zn);
    }
    *(float4*)&X[rb + base]     = make_float4(xn[0], xn[1], xn[2], xn[3]);
    *(float4*)&X[rb + base + 4] = make_float4(xn[4], xn[5], xn[6], xn[7]);
    *(uint4*)&Zb[rb + base] = make_uint4(zp[0], zp[1], zp[2], zp[3]);
  }
}

// ---------------- final fp32 GEMM (exact objective): T = X @ A - Y ----------------
__global__ __launch_bounds__(256) void gemm_ta_kernel(const float* __restrict__ Zm,
                                                      const float* __restrict__ A,
                                                      const float* __restrict__ Y,
                                                      float* __restrict__ T) {
  __shared__ float Zs[64][17];
  __shared__ float As[16][64];
  const int tid = threadIdx.x;
  const int row0 = blockIdx.y * 64, col0 = blockIdx.x * 64;
  const int tx = tid & 15, ty = tid >> 4;
  const int lr = tid >> 2;
  const int lk = (tid & 3) * 4;
  const int ak = tid >> 4;
  const int ac = (tid & 15) * 4;
  float acc[4][4] = {};
  for (int k0 = 0; k0 < N; k0 += 16) {
    float4 z4 = *(const float4*)(Zm + (size_t)(row0 + lr) * N + k0 + lk);
    float4 a4 = *(const float4*)(A + (size_t)(k0 + ak) * D + col0 + ac);
    Zs[lr][lk + 0] = z4.x; Zs[lr][lk + 1] = z4.y; Zs[lr][lk + 2] = z4.z; Zs[lr][lk + 3] = z4.w;
    *(float4*)&As[ak][ac] = a4;
    __syncthreads();
#pragma unroll
    for (int kk = 0; kk < 16; ++kk) {
      float ar[4], br[4];
#pragma unroll
      for (int i = 0; i < 4; ++i) ar[i] = Zs[ty * 4 + i][kk];
#pragma unroll
      for (int j = 0; j < 4; ++j) br[j] = As[kk][tx * 4 + j];
#pragma unroll
      for (int i = 0; i < 4; ++i)
#pragma unroll
        for (int j = 0; j < 4; ++j) acc[i][j] = fmaf(ar[i], br[j], acc[i][j]);
    }
    __syncthreads();
  }
#pragma unroll
  for (int i = 0; i < 4; ++i) {
    int r = row0 + ty * 4 + i;
#pragma unroll
    for (int j = 0; j < 4; ++j) {
      int c = col0 + tx * 4 + j;
      T[(size_t)r * D + c] = acc[i][j] - Y[(size_t)r * D + c];
    }
  }
}

// ---------------- final reduction: out = -mean(T^2) ----------------
__global__ void zero_out_kernel(float* __restrict__ out) {
  if (threadIdx.x == 0 && blockIdx.x == 0) out[0] = 0.f;
}

__global__ __launch_bounds__(256) void mse_reduce_kernel(const float* __restrict__ T,
                                                         float* __restrict__ out) {
  size_t i = (size_t)blockIdx.x * blockDim.x + threadIdx.x;
  size_t total = (size_t)N * D;
  size_t stride = (size_t)gridDim.x * blockDim.x;
  float acc = 0.f;
  for (size_t idx = i; idx < total; idx += stride) {
    float t = T[idx];
    acc = fmaf(t, t, acc);
  }
  acc = wave_reduce_sum(acc);
  __shared__ float sred[4];
  int wid = threadIdx.x >> 6, lane = threadIdx.x & 63;
  if (lane == 0) sred[wid] = acc;
  __syncthreads();
  if (threadIdx.x == 0) {
    float tot = sred[0] + sred[1] + sred[2] + sred[3];
    atomicAdd(out, -tot / (float)((size_t)N * D));
  }
}

extern "C" void kernel_launch(void* const* d_in, const int* in_sizes, int n_in,
                              void* d_out, int out_size, void* d_ws, size_t ws_size,
                              hipStream_t stream) {
  const float* fea1 = (const float*)d_in[0];
  const float* fea2 = (const float*)d_in[1];
  float* out = (float*)d_out;
  float* ws = (float*)d_ws;

  // workspace layout (floats first, then u16; all 64B-aligned)
  float* A   = ws;                        // [N*D] fp32 nfea2
  float* Y   = A + (size_t)N * D;         // [N*D] fp32 nfea1
  float* X   = Y + (size_t)N * D;         // [N*N] fp32
  float* T   = X + (size_t)N * N;         // [N*D] fp32 (final objective)
  float* vv  = T + (size_t)N * D;         // [N]
  float* uu  = vv + N;                    // [D]
  float* wv  = uu + D;                    // [N]
  float* sp  = wv + N;                    // [16] step
  u16* Zb    = (u16*)(sp + 16);           // [N*N] bf16 Z
  u16* Gb    = Zb + (size_t)N * N;        // [N*N] bf16 G = T@A^T
  u16* Tb    = Gb + (size_t)N * N;        // [N*D] bf16 T
  u16* Ab    = Tb + (size_t)N * D;        // [N*D] bf16 A
  u16* AbT   = Ab + (size_t)N * D;        // [D*N] bf16 A^T
  // total ~50 MB

  rownorm_kernel<<<2 * N, 256, 0, stream>>>(fea1, fea2, Y, A);
  prep_kernel<<<dim3(D / 32, N / 32), 256, 0, stream>>>(A, Ab, AbT);
  fill_init<<<2048, 256, 0, stream>>>(X, Zb, vv);

  for (int it = 0; it < POWER_ITERS; ++it) {
    atv_kernel<<<D / 64, 256, 0, stream>>>(A, vv, uu);
    av_kernel<<<N / 4, 256, 0, stream>>>(A, uu, wv);
    normscale_kernel<<<1, 1024, 0, stream>>>(wv, vv);
  }
  atv_kernel<<<D / 64, 256, 0, stream>>>(A, vv, uu);
  av_kernel<<<N / 4, 256, 0, stream>>>(A, uu, wv);
  dotstep_kernel<<<1, 1024, 0, stream>>>(vv, wv, sp);

  float t = 1.0f;
  for (int it = 0; it < N_ITERS; ++it) {
    float tn = 0.5f * (1.0f + sqrtf(1.0f + 4.0f * t * t));
    float beta = (t - 1.0f) / tn;
    t = tn;
    gemm1_mfma<<<dim3(D / 64, N / 64), 256, 0, stream>>>(Zb, AbT, Y, Tb);
    gemm2_mfma<<<dim3(N / 128, N / 128), 256, 0, stream>>>(Tb, Ab, Gb);
    prox_kernel<<<N / 4, 256, 0, stream>>>(Gb, Zb, X, sp, beta);
  }

  // exact fp32 objective on the final X
  gemm_ta_kernel<<<dim3(D / 64, N / 64), 256, 0, stream>>>(X, A, Y, T);
  zero_out_kernel<<<1, 64, 0, stream>>>(out);
  mse_reduce_kernel<<<512, 256, 0, stream>>>(T, out);
}

// Round 5
// 10444.829 us; speedup vs baseline: 4.7112x; 1.1425x over previous
//
#include <hip/hip_runtime.h>
#include <cmath>

#define N 2048
#define D 512
#define N_ITERS 200
#define NEWTON_ITERS 16
#define POWER_ITERS 30

typedef unsigned short u16;
typedef __bf16 bf16x8 __attribute__((ext_vector_type(8)));
typedef float f32x4 __attribute__((ext_vector_type(4)));

__device__ __forceinline__ float wave_reduce_sum(float x) {
#pragma unroll
  for (int o = 32; o > 0; o >>= 1) x += __shfl_xor(x, o, 64);
  return x;
}

__device__ __forceinline__ u16 f2b(float f) {  // fp32 -> bf16 RNE
  unsigned int u = __float_as_uint(f);
  u = (u + 0x7FFFu + ((u >> 16) & 1u)) >> 16;
  return (u16)u;
}

__device__ __forceinline__ float b2f(unsigned int lo16) {
  return __uint_as_float((lo16 & 0xffffu) << 16);
}

// async 16B global->LDS (wave-uniform LDS base + lane*16; per-lane global src)
__device__ __forceinline__ void gload16(const u16* g, u16* l) {
  __builtin_amdgcn_global_load_lds(
      (const __attribute__((address_space(1))) unsigned int*)g,
      (__attribute__((address_space(3))) unsigned int*)l, 16, 0, 0);
}

// ---------------- row normalization: Y = fea1/||row||, A = fea2/||row|| ----------------
__global__ __launch_bounds__(256) void rownorm_kernel(const float* __restrict__ fea1,
                                                      const float* __restrict__ fea2,
                                                      float* __restrict__ Y,
                                                      float* __restrict__ A) {
  int b = blockIdx.x;
  int row = b & (N - 1);
  const float* src = (b < N) ? fea1 : fea2;
  float* dst = (b < N) ? Y : A;
  const float2* s2 = (const float2*)(src + (size_t)row * D);
  float2* d2 = (float2*)(dst + (size_t)row * D);
  int t = threadIdx.x;
  float2 v = s2[t];
  float ss = v.x * v.x + v.y * v.y;
  ss = wave_reduce_sum(ss);
  __shared__ float sred[4];
  int wid = t >> 6, lane = t & 63;
  if (lane == 0) sred[wid] = ss;
  __syncthreads();
  if (t == 0) sred[0] = sred[0] + sred[1] + sred[2] + sred[3];
  __syncthreads();
  float inv = 1.0f / sqrtf(sred[0]);
  d2[t] = make_float2(v.x * inv, v.y * inv);
}

// ---------------- prep: Ab = bf16(A), AbT = bf16(A)^T ----------------
__global__ __launch_bounds__(256) void prep_kernel(const float* __restrict__ A,
                                                   u16* __restrict__ Ab,
                                                   u16* __restrict__ AbT) {
  __shared__ float tile[32][33];
  int c0 = blockIdx.x * 32, r0 = blockIdx.y * 32;
  int tid = threadIdx.x;
  int r = tid >> 3, q = tid & 7;
  float4 v = *(const float4*)&A[(size_t)(r0 + r) * D + c0 + q * 4];
  tile[r][q * 4 + 0] = v.x; tile[r][q * 4 + 1] = v.y;
  tile[r][q * 4 + 2] = v.z; tile[r][q * 4 + 3] = v.w;
  ushort4 b4 = make_ushort4(f2b(v.x), f2b(v.y), f2b(v.z), f2b(v.w));
  *(ushort4*)&Ab[(size_t)(r0 + r) * D + c0 + q * 4] = b4;
  __syncthreads();
  int c = tid >> 3, qq = tid & 7;
  ushort4 t4 = make_ushort4(f2b(tile[qq * 4 + 0][c]), f2b(tile[qq * 4 + 1][c]),
                            f2b(tile[qq * 4 + 2][c]), f2b(tile[qq * 4 + 3][c]));
  *(ushort4*)&AbT[(size_t)(c0 + c) * N + r0 + qq * 4] = t4;
}

// ---------------- init Zb = Xb = bf16(1/N), v = 1/N ----------------
__global__ __launch_bounds__(256) void fill_init(u16* __restrict__ Zb, u16* __restrict__ Xb,
                                                 float* __restrict__ v) {
  const float c = 1.0f / (float)N;
  const unsigned int cw = (unsigned int)f2b(c);
  const unsigned int pp = cw | (cw << 16);
  size_t i = (size_t)blockIdx.x * blockDim.x + threadIdx.x;  // 0 .. N*N/8-1
  uint4 val = make_uint4(pp, pp, pp, pp);
  ((uint4*)Zb)[i] = val;
  ((uint4*)Xb)[i] = val;
  if (i < N) v[i] = c;
}

// ---------------- power iteration (Q v = A (A^T v)), bf16 A, no per-iter normalize ------
__global__ __launch_bounds__(256) void atv_kernel(const u16* __restrict__ Ab,
                                                  const float* __restrict__ v,
                                                  float* __restrict__ u) {
  __shared__ float part[4][64];
  int lane = threadIdx.x & 63, wid = threadIdx.x >> 6;
  int d = blockIdx.x * 64 + lane;
  float acc = 0.f;
  int r0 = wid * 512;
  for (int i = 0; i < 512; ++i) {
    int r = r0 + i;
    acc = fmaf(b2f(Ab[(size_t)r * D + d]), v[r], acc);
  }
  part[wid][lane] = acc;
  __syncthreads();
  if (wid == 0) u[d] = part[0][lane] + part[1][lane] + part[2][lane] + part[3][lane];
}

__global__ __launch_bounds__(256) void av_kernel(const u16* __restrict__ Ab,
                                                 const float* __restrict__ u,
                                                 float* __restrict__ w) {
  int wid = threadIdx.x >> 6, lane = threadIdx.x & 63;
  int row = blockIdx.x * 4 + wid;
  uint4 q = *(const uint4*)&Ab[(size_t)row * D + lane * 8];
  float4 u0 = *(const float4*)&u[lane * 8];
  float4 u1 = *(const float4*)&u[lane * 8 + 4];
  float acc = 0.f;
  acc = fmaf(b2f(q.x), u0.x, acc);
  acc = fmaf(b2f(q.x >> 16), u0.y, acc);
  acc = fmaf(b2f(q.y), u0.z, acc);
  acc = fmaf(b2f(q.y >> 16), u0.w, acc);
  acc = fmaf(b2f(q.z), u1.x, acc);
  acc = fmaf(b2f(q.z >> 16), u1.y, acc);
  acc = fmaf(b2f(q.w), u1.z, acc);
  acc = fmaf(b2f(q.w >> 16), u1.w, acc);
  acc = wave_reduce_sum(acc);
  if (lane == 0) w[row] = acc * 0.0625f;   // fixed 1/16 rescale keeps fp32 range
}

// lam = 16 * (v.w)/(v.v)   [w = Qv/16]; step = 1/(2 lam + 1e-12)
__global__ __launch_bounds__(1024) void rayleigh_kernel(const float* __restrict__ v,
                                                        const float* __restrict__ w,
                                                        float* __restrict__ step) {
  int t = threadIdx.x;
  float a0 = v[t], a1 = v[t + 1024];
  float b0 = w[t], b1 = w[t + 1024];
  float s1 = a0 * b0 + a1 * b1;
  float s2 = a0 * a0 + a1 * a1;
  s1 = wave_reduce_sum(s1);
  s2 = wave_reduce_sum(s2);
  __shared__ float r1[16], r2[16];
  int wid = t >> 6, lane = t & 63;
  if (lane == 0) { r1[wid] = s1; r2[wid] = s2; }
  __syncthreads();
  if (t == 0) {
    float t1 = 0.f, t2 = 0.f;
#pragma unroll
    for (int i = 0; i < 16; ++i) { t1 += r1[i]; t2 += r2[i]; }
    float lam = 16.0f * t1 / t2;
    step[0] = 1.0f / (2.0f * lam + 1e-12f);
  }
}

// ================= MFMA GEMMs: gload_lds + XOR-swizzle + 2-phase dbuf =================

// GEMM1: out = (Zb @ A) - Y.  M=2048, cols=512, K=2048. 64x64 tile, BK=128, 16 steps.
// 256 thr / 4 waves (2x2, wave tile 32x32). LDS row = 128 u16 = 16 slots of 16B;
// slot s of row r stored at s^(r&15) (inverse applied on global src, same XOR on read).
// FOUT=0: bf16 out (Tb); FOUT=1: fp32 out (final objective T32).
template <int FOUT>
__global__ __launch_bounds__(256) void gemm1_mfma(const u16* __restrict__ Am,
                                                  const u16* __restrict__ Bm,
                                                  const float* __restrict__ Y,
                                                  u16* __restrict__ outb,
                                                  float* __restrict__ outf) {
  __shared__ u16 lds[2 * 16384];  // [buf][A 8192 | B 8192]
  const int tid = threadIdx.x, lane = tid & 63, wid = tid >> 6;
  const int row0 = blockIdx.y * 64, col0 = blockIdx.x * 64;
  const int wr = (wid >> 1) * 32, wc = (wid & 1) * 32;
  const int fr = lane & 15, h = lane >> 4;
  const int grow = lane >> 4, gslot = lane & 15;  // staging: 4 rows / wave-instr
  f32x4 acc[2][2] = {};

#define G1_STAGE(BUF, T)                                                        \
  {                                                                             \
    const int k0 = (T) * 128;                                                   \
    _Pragma("unroll") for (int q = 0; q < 4; ++q) {                             \
      const int m = wid * 4 + q;                                                \
      const int r = m * 4 + grow;                                               \
      const int kl = (gslot ^ (r & 15)) * 8;                                    \
      gload16(&Am[(size_t)(row0 + r) * 2048 + k0 + kl],                         \
              &lds[(BUF) * 16384 + m * 512]);                                   \
      gload16(&Bm[(size_t)(col0 + r) * 2048 + k0 + kl],                         \
              &lds[(BUF) * 16384 + 8192 + m * 512]);                            \
    }                                                                           \
  }

  G1_STAGE(0, 0);
  __syncthreads();
#pragma unroll 2
  for (int t = 0; t < 16; ++t) {
    const int buf = (t & 1) * 16384;
    if (t < 15) G1_STAGE((t & 1) ^ 1, t + 1);
    bf16x8 af[2][4], bg[2][4];
#pragma unroll
    for (int i = 0; i < 2; ++i) {
      const int r = wr + i * 16 + fr;
#pragma unroll
      for (int ks = 0; ks < 4; ++ks)
        af[i][ks] = *(const bf16x8*)&lds[buf + r * 128 + ((((ks << 2) + h) ^ (r & 15)) << 3)];
    }
#pragma unroll
    for (int j = 0; j < 2; ++j) {
      const int c = wc + j * 16 + fr;
#pragma unroll
      for (int ks = 0; ks < 4; ++ks)
        bg[j][ks] = *(const bf16x8*)&lds[buf + 8192 + c * 128 + ((((ks << 2) + h) ^ (c & 15)) << 3)];
    }
#pragma unroll
    for (int ks = 0; ks < 4; ++ks)
#pragma unroll
      for (int i = 0; i < 2; ++i)
#pragma unroll
        for (int j = 0; j < 2; ++j)
          acc[i][j] = __builtin_amdgcn_mfma_f32_16x16x32_bf16(af[i][ks], bg[j][ks], acc[i][j], 0, 0, 0);
    __syncthreads();
  }
#pragma unroll
  for (int i = 0; i < 2; ++i)
#pragma unroll
    for (int j = 0; j < 2; ++j)
#pragma unroll
      for (int g = 0; g < 4; ++g) {
        int r = row0 + wr + i * 16 + h * 4 + g;
        int c = col0 + wc + j * 16 + fr;
        float val = acc[i][j][g] - Y[(size_t)r * D + c];
        if (FOUT) outf[(size_t)r * D + c] = val;
        else      outb[(size_t)r * D + c] = f2b(val);
      }
#undef G1_STAGE
}

// GEMM2: Gb = bf16( Tb @ Ab^T ), M=N=2048, K=512. 128x128 tile, BK=64, 8 steps.
// 512 thr / 8 waves (2x4, wave tile 64x32). Row = 64 u16 = 8 slots; XOR (r&7).
__global__ __launch_bounds__(512) void gemm2_mfma(const u16* __restrict__ Tb,
                                                  const u16* __restrict__ Ab,
                                                  u16* __restrict__ Gb) {
  __shared__ u16 lds[2 * 16384];  // [buf][A 8192 | B 8192]
  const int tid = threadIdx.x, lane = tid & 63, wid = tid >> 6;
  const int row0 = blockIdx.y * 128, col0 = blockIdx.x * 128;
  const int wr = (wid >> 2) * 64, wc = (wid & 3) * 32;
  const int fr = lane & 15, h = lane >> 4;
  const int grow = lane >> 3, gslot = lane & 7;  // staging: 8 rows / wave-instr
  f32x4 acc[4][2] = {};

#define G2_STAGE(BUF, T)                                                        \
  {                                                                             \
    const int k0 = (T) * 64;                                                    \
    _Pragma("unroll") for (int q = 0; q < 2; ++q) {                             \
      const int m = wid * 2 + q;                                                \
      const int r = m * 8 + grow;                                               \
      const int kl = (gslot ^ (r & 7)) * 8;                                     \
      gload16(&Tb[(size_t)(row0 + r) * 512 + k0 + kl],                          \
              &lds[(BUF) * 16384 + m * 512]);                                   \
      gload16(&Ab[(size_t)(col0 + r) * 512 + k0 + kl],                          \
              &lds[(BUF) * 16384 + 8192 + m * 512]);                            \
    }                                                                           \
  }

  G2_STAGE(0, 0);
  __syncthreads();
#pragma unroll 2
  for (int t = 0; t < 8; ++t) {
    const int buf = (t & 1) * 16384;
    if (t < 7) G2_STAGE((t & 1) ^ 1, t + 1);
    bf16x8 af[4][2], bg[2][2];
#pragma unroll
    for (int i = 0; i < 4; ++i) {
      const int r = wr + i * 16 + fr;
#pragma unroll
      for (int ks = 0; ks < 2; ++ks)
        af[i][ks] = *(const bf16x8*)&lds[buf + r * 64 + ((((ks << 2) + h) ^ (r & 7)) << 3)];
    }
#pragma unroll
    for (int j = 0; j < 2; ++j) {
      const int c = wc + j * 16 + fr;
#pragma unroll
      for (int ks = 0; ks < 2; ++ks)
        bg[j][ks] = *(const bf16x8*)&lds[buf + 8192 + c * 64 + ((((ks << 2) + h) ^ (c & 7)) << 3)];
    }
#pragma unroll
    for (int ks = 0; ks < 2; ++ks)
#pragma unroll
      for (int i = 0; i < 4; ++i)
#pragma unroll
        for (int j = 0; j < 2; ++j)
          acc[i][j] = __builtin_amdgcn_mfma_f32_16x16x32_bf16(af[i][ks], bg[j][ks], acc[i][j], 0, 0, 0);
    __syncthreads();
  }
#pragma unroll
  for (int i = 0; i < 4; ++i)
#pragma unroll
    for (int j = 0; j < 2; ++j)
#pragma unroll
      for (int g = 0; g < 4; ++g) {
        int r = row0 + wr + i * 16 + h * 4 + g;
        int c = col0 + wc + j * 16 + fr;
        Gb[(size_t)r * N + c] = f2b(acc[i][j][g]);
      }
#undef G2_STAGE
}

// ---------------- prox: v = z - 2s*g; capped-simplex projection (Newton); momentum -----
__global__ __launch_bounds__(256) void prox_kernel(const u16* __restrict__ Gb,
                                                   u16* __restrict__ Zb,
                                                   u16* __restrict__ Xb,
                                                   const float* __restrict__ stepp,
                                                   float beta) {
  const int wid = threadIdx.x >> 6, lane = threadIdx.x & 63;
  const int row = blockIdx.x * 4 + wid;
  const size_t rb = (size_t)row * N;
  const float s2 = 2.0f * stepp[0];
  float v[32], xo[32];
  float mn = 1e30f, mx = -1e30f;
#pragma unroll
  for (int c = 0; c < 4; ++c) {
    const int base = c * 512 + lane * 8;
    uint4 zu = *(const uint4*)&Zb[rb + base];
    uint4 gu = *(const uint4*)&Gb[rb + base];
    uint4 xu = *(const uint4*)&Xb[rb + base];
    const unsigned int zw[4] = {zu.x, zu.y, zu.z, zu.w};
    const unsigned int gw[4] = {gu.x, gu.y, gu.z, gu.w};
    const unsigned int xw[4] = {xu.x, xu.y, xu.z, xu.w};
#pragma unroll
    for (int w = 0; w < 4; ++w) {
      int e = c * 8 + w * 2;
      float v0 = b2f(zw[w]) - s2 * b2f(gw[w]);
      float v1 = __uint_as_float(zw[w] & 0xffff0000u) - s2 * __uint_as_float(gw[w] & 0xffff0000u);
      v[e] = v0; v[e + 1] = v1;
      xo[e] = b2f(xw[w]); xo[e + 1] = __uint_as_float(xw[w] & 0xffff0000u);
      mn = fminf(mn, fminf(v0, v1));
      mx = fmaxf(mx, fmaxf(v0, v1));
    }
  }
#pragma unroll
  for (int o = 32; o > 0; o >>= 1) {
    mn = fminf(mn, __shfl_xor(mn, o, 64));
    mx = fmaxf(mx, __shfl_xor(mx, o, 64));
  }
  // f(tau) = sum clamp(v - tau, 0, 1) - 1, piecewise-linear decreasing.
  // Safeguarded Newton: bracket update like the reference bisection; Newton
  // proposal mid + (s-1)/cnt (f' = -cnt) accepted only inside the bracket.
  float lo = mn - 1.0f, hi = mx;
  float mid = 0.5f * (lo + hi);
#pragma unroll 1
  for (int it = 0; it < NEWTON_ITERS; ++it) {
    float s = 0.f, cnt = 0.f;
#pragma unroll
    for (int e = 0; e < 32; ++e) {
      float d = v[e] - mid;
      s += fminf(fmaxf(d, 0.f), 1.f);
      cnt += (d > 0.f && d < 1.f) ? 1.f : 0.f;
    }
    s = wave_reduce_sum(s);
    cnt = wave_reduce_sum(cnt);
    bool gt = s > 1.0f;
    lo = gt ? mid : lo;
    hi = gt ? hi : mid;
    float prop = mid + (s - 1.0f) / fmaxf(cnt, 0.5f);
    mid = (prop > lo && prop < hi) ? prop : 0.5f * (lo + hi);
  }
  float tau = mid;
#pragma unroll
  for (int c = 0; c < 4; ++c) {
    const int base = c * 512 + lane * 8;
    unsigned int xp[4], zp[4];
#pragma unroll
    for (int q = 0; q < 8; ++q) {
      int e = c * 8 + q;
      float x = fminf(fmaxf(v[e] - tau, 0.f), 1.f);
      float zn = x + beta * (x - xo[e]);
      unsigned int xb = (unsigned int)f2b(x);
      unsigned int zb = (unsigned int)f2b(zn);
      if (q & 1) { xp[q >> 1] |= xb << 16; zp[q >> 1] |= zb << 16; }
      else       { xp[q >> 1] = xb;        zp[q >> 1] = zb; }
    }
    *(uint4*)&Xb[rb + base] = make_uint4(xp[0], xp[1], xp[2], xp[3]);
    *(uint4*)&Zb[rb + base] = make_uint4(zp[0], zp[1], zp[2], zp[3]);
  }
}

// ---------------- final reduction: out = -mean(T32^2) ----------------
__global__ void zero_out_kernel(float* __restrict__ out) {
  if (threadIdx.x == 0 && blockIdx.x == 0) out[0] = 0.f;
}

__global__ __launch_bounds__(256) void mse_reduce_kernel(const float* __restrict__ T,
                                                         float* __restrict__ out) {
  size_t i = (size_t)blockIdx.x * blockDim.x + threadIdx.x;
  size_t total = (size_t)N * D;
  size_t stride = (size_t)gridDim.x * blockDim.x;
  float acc = 0.f;
  for (size_t idx = i; idx < total; idx += stride) {
    float t = T[idx];
    acc = fmaf(t, t, acc);
  }
  acc = wave_reduce_sum(acc);
  __shared__ float sred[4];
  int wid = threadIdx.x >> 6, lane = threadIdx.x & 63;
  if (lane == 0) sred[wid] = acc;
  __syncthreads();
  if (threadIdx.x == 0) {
    float tot = sred[0] + sred[1] + sred[2] + sred[3];
    atomicAdd(out, -tot / (float)((size_t)N * D));
  }
}

extern "C" void kernel_launch(void* const* d_in, const int* in_sizes, int n_in,
                              void* d_out, int out_size, void* d_ws, size_t ws_size,
                              hipStream_t stream) {
  const float* fea1 = (const float*)d_in[0];
  const float* fea2 = (const float*)d_in[1];
  float* out = (float*)d_out;
  float* ws = (float*)d_ws;

  // workspace layout (~42 MB, all 16B-aligned)
  float* A   = ws;                        // [N*D] fp32 nfea2
  float* Y   = A + (size_t)N * D;         // [N*D] fp32 nfea1
  float* T32 = Y + (size_t)N * D;         // [N*D] fp32 final residual
  float* vv  = T32 + (size_t)N * D;       // [N]
  float* wv  = vv + N;                    // [N]
  float* uu  = wv + N;                    // [D]
  float* sp  = uu + D;                    // [16] step
  u16* Zb    = (u16*)(sp + 16);           // [N*N] bf16 Z
  u16* Gb    = Zb + (size_t)N * N;        // [N*N] bf16 G = T@A^T
  u16* Xb    = Gb + (size_t)N * N;        // [N*N] bf16 X
  u16* Tb    = Xb + (size_t)N * N;        // [N*D] bf16 T
  u16* Ab    = Tb + (size_t)N * D;        // [N*D] bf16 A
  u16* AbT   = Ab + (size_t)N * D;        // [D*N] bf16 A^T

  rownorm_kernel<<<2 * N, 256, 0, stream>>>(fea1, fea2, Y, A);
  prep_kernel<<<dim3(D / 32, N / 32), 256, 0, stream>>>(A, Ab, AbT);
  fill_init<<<(N * N / 8) / 256, 256, 0, stream>>>(Zb, Xb, vv);

  // power iteration, unnormalized with fixed 1/16 rescale (direction-invariant)
  float* pv = vv;
  float* pw = wv;
  for (int it = 0; it < POWER_ITERS; ++it) {
    atv_kernel<<<D / 64, 256, 0, stream>>>(Ab, pv, uu);
    av_kernel<<<N / 4, 256, 0, stream>>>(Ab, uu, pw);
    float* tmp = pv; pv = pw; pw = tmp;
  }
  atv_kernel<<<D / 64, 256, 0, stream>>>(Ab, pv, uu);
  av_kernel<<<N / 4, 256, 0, stream>>>(Ab, uu, pw);
  rayleigh_kernel<<<1, 1024, 0, stream>>>(pv, pw, sp);

  float t = 1.0f;
  for (int it = 0; it < N_ITERS; ++it) {
    float tn = 0.5f * (1.0f + sqrtf(1.0f + 4.0f * t * t));
    float beta = (t - 1.0f) / tn;
    t = tn;
    gemm1_mfma<0><<<dim3(D / 64, N / 64), 256, 0, stream>>>(Zb, AbT, Y, Tb, T32);
    gemm2_mfma<<<dim3(N / 128, N / 128), 512, 0, stream>>>(Tb, Ab, Gb);
    prox_kernel<<<N / 4, 256, 0, stream>>>(Gb, Zb, Xb, sp, beta);
  }

  // final objective from Xb (bf16 MFMA, fp32 residual)
  gemm1_mfma<1><<<dim3(D / 64, N / 64), 256, 0, stream>>>(Xb, AbT, Y, Tb, T32);
  zero_out_kernel<<<1, 64, 0, stream>>>(out);
  mse_reduce_kernel<<<512, 256, 0, stream>>>(T32, out);
}